// Round 8
// baseline (280.216 us; speedup 1.0000x reference)
//
#include <hip/hip_runtime.h>

typedef __bf16 bf16_t;
typedef __bf16 bf16x4v __attribute__((ext_vector_type(4)));
typedef __bf16 bf16x8 __attribute__((ext_vector_type(8)));
typedef float f32x4 __attribute__((ext_vector_type(4)));

constexpr int TT = 2048;
constexpr int DDIM = 1024;

// workspace layout (bf16 element offsets)
constexpr size_t SZ_TD  = (size_t)2048 * 1024;
constexpr size_t OFF_QU = 0;                     // Qu[h][t][dh] = q + u
constexpr size_t OFF_QV = 1 * SZ_TD;             // Qv[h][t][dh] = q + v_bias
constexpr size_t OFF_KK = 2 * SZ_TD;             // K [h][t][dh]
constexpr size_t OFF_RR = 3 * SZ_TD;             // Rrev[h][c][dh] = R[T-1-c]
constexpr size_t OFF_VT = 4 * SZ_TD;             // Vt[h][dh][t]
constexpr size_t OFF_AO = 5 * SZ_TD;             // attnout[t][d]
constexpr size_t OFF_XB = 6 * SZ_TD;             // x bf16; REUSED: attn partial O chunk 0
constexpr size_t OFF_RB = 7 * SZ_TD;             // r_emb ; REUSED: attn partial O chunk 1
constexpr size_t OFF_WT = 8 * SZ_TD;             // Wt[5][n][k]; after proj: Wq slot = ml float2
constexpr size_t SZ_W   = (size_t)1024 * 1024;

__device__ __forceinline__ f32x4 fzero4() {
  f32x4 z; z[0] = 0.f; z[1] = 0.f; z[2] = 0.f; z[3] = 0.f; return z;
}

__device__ __forceinline__ void gload16(const bf16_t* g, bf16_t* l) {
  __builtin_amdgcn_global_load_lds((const __attribute__((address_space(1))) void*)g,
                                   (__attribute__((address_space(3))) void*)l, 16, 0, 0);
}

// ---------------- prep 1: fp32 -> bf16 for x and r_emb ----------------
__global__ __launch_bounds__(256) void convert_kernel(const float* __restrict__ x,
                                                      const float* __restrict__ r,
                                                      bf16_t* __restrict__ ws) {
  const int i = blockIdx.x * 256 + threadIdx.x;
  float4 a = ((const float4*)x)[i];
  float4 b = ((const float4*)r)[i];
  bf16x4v av, bv;
  av[0] = (bf16_t)a.x; av[1] = (bf16_t)a.y; av[2] = (bf16_t)a.z; av[3] = (bf16_t)a.w;
  bv[0] = (bf16_t)b.x; bv[1] = (bf16_t)b.y; bv[2] = (bf16_t)b.z; bv[3] = (bf16_t)b.w;
  ((bf16x4v*)(ws + OFF_XB))[i] = av;
  ((bf16x4v*)(ws + OFF_RB))[i] = bv;
}

// ---------------- prep 2: W[k][n] fp32 -> Wt[n][k] bf16, 5 weights ----------------
__global__ __launch_bounds__(256) void transpose_w_kernel(const float* __restrict__ Wq,
                                                          const float* __restrict__ Wk,
                                                          const float* __restrict__ Wv,
                                                          const float* __restrict__ Wr,
                                                          const float* __restrict__ Wo,
                                                          bf16_t* __restrict__ ws) {
  const int k0 = blockIdx.x * 64, n0 = blockIdx.y * 64, wsel = blockIdx.z;
  const float* W = (wsel == 0) ? Wq : (wsel == 1) ? Wk : (wsel == 2) ? Wv : (wsel == 3) ? Wr : Wo;
  bf16_t* Wt = ws + OFF_WT + (size_t)wsel * SZ_W;
  __shared__ float tile[64][65];
  const int tid = threadIdx.x;
#pragma unroll
  for (int it = 0; it < 4; ++it) {
    int g = tid + it * 256; int rr = g >> 4; int c4 = (g & 15) * 4;
    float4 v = *(const float4*)&W[(size_t)(k0 + rr) * DDIM + n0 + c4];
    tile[rr][c4] = v.x; tile[rr][c4 + 1] = v.y; tile[rr][c4 + 2] = v.z; tile[rr][c4 + 3] = v.w;
  }
  __syncthreads();
#pragma unroll
  for (int it = 0; it < 4; ++it) {
    int g = tid + it * 256; int nr = g >> 4; int c4 = (g & 15) * 4;
    bf16x4v o;
    o[0] = (bf16_t)tile[c4 + 0][nr]; o[1] = (bf16_t)tile[c4 + 1][nr];
    o[2] = (bf16_t)tile[c4 + 2][nr]; o[3] = (bf16_t)tile[c4 + 3][nr];
    *(bf16x4v*)&Wt[(size_t)(n0 + nr) * DDIM + k0 + c4] = o;
  }
}

// ---------------- projections, fused QKV + R ----------------
// grid (16,16,2): z=0 -> Q,K,V share the A=x staging (24 MFMA per k-iter);
//                 z=1 -> R (A=r_emb). 128x64 output tiles.
__global__ __launch_bounds__(256) void proj_kernel(const bf16_t* wsc, bf16_t* wsd,
                                                   const float* __restrict__ u,
                                                   const float* __restrict__ vb) {
  const int zr = blockIdx.z;
  const int i0 = blockIdx.x * 128, n0 = blockIdx.y * 64;
  __shared__ bf16_t As[128 * 32];
  __shared__ bf16_t Bs[3][64 * 32];
  const int tid = threadIdx.x, lane = tid & 63, wv = tid >> 6;
  const int wr = (wv >> 1) * 64, wc = (wv & 1) * 32;
  const int sr = tid >> 2, scc = (tid & 3) * 8;
  const int l15 = lane & 15, lg8 = (lane >> 4) * 8, lr4 = (lane >> 4) * 4;

  if (zr == 0) {
    const bf16_t* A  = wsc + OFF_XB;
    const bf16_t* Bq = wsc + OFF_WT;
    const bf16_t* Bk = wsc + OFF_WT + 1 * SZ_W;
    const bf16_t* Bv = wsc + OFF_WT + 2 * SZ_W;
    f32x4 accq[4][2], acck[4][2], accv[4][2];
#pragma unroll
    for (int m = 0; m < 4; ++m)
#pragma unroll
      for (int n = 0; n < 2; ++n) { accq[m][n] = fzero4(); acck[m][n] = fzero4(); accv[m][n] = fzero4(); }

    for (int k0 = 0; k0 < DDIM; k0 += 32) {
      __syncthreads();
      gload16(&A[(size_t)(i0 + sr) * DDIM + k0 + scc],      &As[sr * 32 + scc]);
      gload16(&A[(size_t)(i0 + 64 + sr) * DDIM + k0 + scc], &As[(64 + sr) * 32 + scc]);
      gload16(&Bq[(size_t)(n0 + sr) * DDIM + k0 + scc],     &Bs[0][sr * 32 + scc]);
      gload16(&Bk[(size_t)(n0 + sr) * DDIM + k0 + scc],     &Bs[1][sr * 32 + scc]);
      gload16(&Bv[(size_t)(n0 + sr) * DDIM + k0 + scc],     &Bs[2][sr * 32 + scc]);
      __syncthreads();
      bf16x8 af[4], bq[2], bk[2], bv[2];
#pragma unroll
      for (int m = 0; m < 4; ++m) af[m] = *(const bf16x8*)&As[(wr + m * 16 + l15) * 32 + lg8];
#pragma unroll
      for (int n = 0; n < 2; ++n) {
        bq[n] = *(const bf16x8*)&Bs[0][(wc + n * 16 + l15) * 32 + lg8];
        bk[n] = *(const bf16x8*)&Bs[1][(wc + n * 16 + l15) * 32 + lg8];
        bv[n] = *(const bf16x8*)&Bs[2][(wc + n * 16 + l15) * 32 + lg8];
      }
#pragma unroll
      for (int m = 0; m < 4; ++m)
#pragma unroll
        for (int n = 0; n < 2; ++n) {
          accq[m][n] = __builtin_amdgcn_mfma_f32_16x16x32_bf16(af[m], bq[n], accq[m][n], 0, 0, 0);
          acck[m][n] = __builtin_amdgcn_mfma_f32_16x16x32_bf16(af[m], bk[n], acck[m][n], 0, 0, 0);
          accv[m][n] = __builtin_amdgcn_mfma_f32_16x16x32_bf16(af[m], bv[n], accv[m][n], 0, 0, 0);
        }
    }

#pragma unroll
    for (int mm = 0; mm < 4; ++mm)
#pragma unroll
      for (int nn = 0; nn < 2; ++nn)
#pragma unroll
        for (int rg = 0; rg < 4; ++rg) {
          const int row = i0 + wr + mm * 16 + lr4 + rg;
          const int col = n0 + wc + nn * 16 + l15;
          const int hh = col >> 6, dh = col & 63;
          wsd[OFF_QU + ((size_t)hh * TT + row) * 64 + dh] = (bf16_t)(accq[mm][nn][rg] + u[col]);
          wsd[OFF_QV + ((size_t)hh * TT + row) * 64 + dh] = (bf16_t)(accq[mm][nn][rg] + vb[col]);
          wsd[OFF_KK + ((size_t)hh * TT + row) * 64 + dh] = (bf16_t)acck[mm][nn][rg];
          wsd[OFF_VT + ((size_t)hh * 64 + dh) * TT + row] = (bf16_t)accv[mm][nn][rg];
        }
  } else {
    const bf16_t* A  = wsc + OFF_RB;
    const bf16_t* Bt = wsc + OFF_WT + 3 * SZ_W;
    f32x4 acc[4][2];
#pragma unroll
    for (int m = 0; m < 4; ++m)
#pragma unroll
      for (int n = 0; n < 2; ++n) acc[m][n] = fzero4();

    for (int k0 = 0; k0 < DDIM; k0 += 32) {
      __syncthreads();
      gload16(&A[(size_t)(i0 + sr) * DDIM + k0 + scc],      &As[sr * 32 + scc]);
      gload16(&A[(size_t)(i0 + 64 + sr) * DDIM + k0 + scc], &As[(64 + sr) * 32 + scc]);
      gload16(&Bt[(size_t)(n0 + sr) * DDIM + k0 + scc],     &Bs[0][sr * 32 + scc]);
      __syncthreads();
      bf16x8 af[4], bfv[2];
#pragma unroll
      for (int m = 0; m < 4; ++m) af[m] = *(const bf16x8*)&As[(wr + m * 16 + l15) * 32 + lg8];
#pragma unroll
      for (int n = 0; n < 2; ++n) bfv[n] = *(const bf16x8*)&Bs[0][(wc + n * 16 + l15) * 32 + lg8];
#pragma unroll
      for (int m = 0; m < 4; ++m)
#pragma unroll
        for (int n = 0; n < 2; ++n)
          acc[m][n] = __builtin_amdgcn_mfma_f32_16x16x32_bf16(af[m], bfv[n], acc[m][n], 0, 0, 0);
    }

#pragma unroll
    for (int mm = 0; mm < 4; ++mm)
#pragma unroll
      for (int nn = 0; nn < 2; ++nn)
#pragma unroll
        for (int rg = 0; rg < 4; ++rg) {
          const int row = i0 + wr + mm * 16 + lr4 + rg;
          const int col = n0 + wc + nn * 16 + l15;
          const int hh = col >> 6, dh = col & 63;
          wsd[OFF_RR + ((size_t)hh * TT + (TT - 1 - row)) * 64 + dh] = (bf16_t)acc[mm][nn][rg];
        }
  }
}

// ---------------- fused XL attention: 2 interleaved q16-tiles per wave -------------
// Shared K/R loads + shared PB/PL LDS (per-wave LDS ops are in-order -> safe).
#define SOFTPV(AC, QBASE, OO, MRUN, LRUN)                                                  \
  {                                                                                        \
    float sc[4][4];                                                                        \
    float smax = -3e38f;                                                                   \
    _Pragma("unroll") for (int nt = 0; nt < 4; ++nt)                                       \
      _Pragma("unroll") for (int rg = 0; rg < 4; ++rg) {                                   \
        const int jj = nt * 16 + lg * 4 + rg;                                              \
        float v = (AC[nt][rg] + PB[(l15 + 63 - jj) * 18 + l15]) * 0.125f;                  \
        v = (j0 + jj > (QBASE) + l15) ? -1e30f : v;                                        \
        smax = fmaxf(smax, v);                                                             \
        sc[nt][rg] = v;                                                                    \
      }                                                                                    \
    smax = fmaxf(smax, __shfl_xor(smax, 16));                                              \
    smax = fmaxf(smax, __shfl_xor(smax, 32));                                              \
    const float newm = fmaxf(MRUN, smax);                                                  \
    const float fac = __expf(MRUN - newm);                                                 \
    MRUN = newm;                                                                           \
    float pv[4][4];                                                                        \
    float rsum = 0.f;                                                                      \
    _Pragma("unroll") for (int nt = 0; nt < 4; ++nt)                                       \
      _Pragma("unroll") for (int rg = 0; rg < 4; ++rg) {                                   \
        pv[nt][rg] = __expf(sc[nt][rg] - newm);                                            \
        rsum += pv[nt][rg];                                                                \
      }                                                                                    \
    rsum += __shfl_xor(rsum, 16);                                                          \
    rsum += __shfl_xor(rsum, 32);                                                          \
    LRUN = LRUN * fac + rsum;                                                              \
    float fo[4];                                                                           \
    _Pragma("unroll") for (int rg = 0; rg < 4; ++rg) fo[rg] = __shfl(fac, lg * 4 + rg);    \
    _Pragma("unroll") for (int d = 0; d < 4; ++d)                                          \
      _Pragma("unroll") for (int rg = 0; rg < 4; ++rg) OO[d][rg] *= fo[rg];                \
    _Pragma("unroll") for (int nt = 0; nt < 4; ++nt) {                                     \
      bf16x4v pk;                                                                          \
      pk[0] = (bf16_t)pv[nt][0]; pk[1] = (bf16_t)pv[nt][1];                                \
      pk[2] = (bf16_t)pv[nt][2]; pk[3] = (bf16_t)pv[nt][3];                                \
      *(bf16x4v*)&PL[l15 * 72 + nt * 16 + lg * 4] = pk;                                    \
    }                                                                                      \
    bf16x8 pf[2];                                                                          \
    _Pragma("unroll") for (int ks = 0; ks < 2; ++ks)                                       \
      pf[ks] = *(const bf16x8*)&PL[l15 * 72 + ks * 32 + lg8];                              \
    _Pragma("unroll") for (int d = 0; d < 4; ++d)                                          \
      _Pragma("unroll") for (int ks = 0; ks < 2; ++ks)                                     \
        OO[d] = __builtin_amdgcn_mfma_f32_16x16x32_bf16(pf[ks], vf[d][ks], OO[d], 0, 0, 0);\
  }

// grid (16, 64, 2): blockIdx.x = head -> linear id % 8 == h % 8 -> head-per-XCD affinity.
__global__ __launch_bounds__(64, 3) void attn_kernel(const bf16_t* wsc, bf16_t* wsd) {
  const int h = blockIdx.x;
  const int chunk = blockIdx.z;
  const int q32 = 63 - blockIdx.y;         // longest blocks first
  const int i0 = q32 * 32;                 // tile1 rows i0..i0+15, tile2 rows i0+16..i0+31
  const int lane = threadIdx.x & 63;
  const int l15 = lane & 15;
  const int lg = lane >> 4;
  const int lg8 = lg * 8;

  const int NT = (i0 >> 6) + 1;
  const int H = (NT + 1) >> 1;
  const int tbeg = chunk ? H : 0;
  const int tend = chunk ? NT : H;

  bf16_t* Po = wsd + ((chunk == 0) ? OFF_XB : OFF_RB) + (size_t)h * TT * 64;
  float2* ml = (float2*)(wsd + OFF_WT) + (size_t)(chunk * 16 + h) * TT;

  if (tbeg >= tend) {                      // empty chunk: neutral partial (32 rows)
#pragma unroll
    for (int m = 0; m < 2; ++m)
#pragma unroll
      for (int d = 0; d < 4; ++d)
#pragma unroll
        for (int rg = 0; rg < 4; ++rg)
          Po[(size_t)(i0 + m * 16 + lg * 4 + rg) * 64 + d * 16 + l15] = (bf16_t)0.f;
    if (lg == 0) { ml[i0 + l15] = make_float2(-3e38f, 0.f); ml[i0 + 16 + l15] = make_float2(-3e38f, 0.f); }
    return;
  }

  const bf16_t* QUp = wsc + OFF_QU + (size_t)h * TT * 64;
  const bf16_t* QVp = wsc + OFF_QV + (size_t)h * TT * 64;
  const bf16_t* Kp  = wsc + OFF_KK + (size_t)h * TT * 64;
  const bf16_t* Rp  = wsc + OFF_RR + (size_t)h * TT * 64;
  const bf16_t* Vp  = wsc + OFF_VT + (size_t)h * 64 * TT;

  __shared__ float PB[80 * 18];            // shared between both chains
  __shared__ bf16_t PL[16 * 72];

  bf16x8 qu1[2], qv1[2], qu2[2], qv2[2];
#pragma unroll
  for (int ks = 0; ks < 2; ++ks) {
    qu1[ks] = *(const bf16x8*)&QUp[(size_t)(i0 + l15) * 64 + ks * 32 + lg8];
    qv1[ks] = *(const bf16x8*)&QVp[(size_t)(i0 + l15) * 64 + ks * 32 + lg8];
    qu2[ks] = *(const bf16x8*)&QUp[(size_t)(i0 + 16 + l15) * 64 + ks * 32 + lg8];
    qv2[ks] = *(const bf16x8*)&QVp[(size_t)(i0 + 16 + l15) * 64 + ks * 32 + lg8];
  }

  f32x4 o1[4], o2[4];
#pragma unroll
  for (int d = 0; d < 4; ++d) { o1[d] = fzero4(); o2[d] = fzero4(); }
  float m1 = -3e38f, l1 = 0.f, m2 = -3e38f, l2 = 0.f;

  for (int t = tbeg; t < tend; ++t) {
    const int j0 = t * 64;
    // ---- K + R band loads ----
    bf16x8 kf[4][2], rf[6][2];
#pragma unroll
    for (int nt = 0; nt < 4; ++nt)
#pragma unroll
      for (int ks = 0; ks < 2; ++ks)
        kf[nt][ks] = *(const bf16x8*)&Kp[(size_t)(j0 + nt * 16 + l15) * 64 + ks * 32 + lg8];
    const int c0 = i0 - j0 - 63;
#pragma unroll
    for (int bt = 0; bt < 6; ++bt) {
      int c = c0 + bt * 16 + l15;
      c = (c < 0) ? 0 : ((c > TT - 1) ? TT - 1 : c);
#pragma unroll
      for (int ks = 0; ks < 2; ++ks)
        rf[bt][ks] = *(const bf16x8*)&Rp[(size_t)c * 64 + ks * 32 + lg8];
    }

    // ---- AC for both tiles ----
    f32x4 ac1[4], ac2[4];
#pragma unroll
    for (int nt = 0; nt < 4; ++nt) { ac1[nt] = fzero4(); ac2[nt] = fzero4(); }
#pragma unroll
    for (int nt = 0; nt < 4; ++nt)
#pragma unroll
      for (int ks = 0; ks < 2; ++ks) {
        ac1[nt] = __builtin_amdgcn_mfma_f32_16x16x32_bf16(kf[nt][ks], qu1[ks], ac1[nt], 0, 0, 0);
        ac2[nt] = __builtin_amdgcn_mfma_f32_16x16x32_bf16(kf[nt][ks], qu2[ks], ac2[nt], 0, 0, 0);
      }

    // ---- BD bands (tile1 uses rf[0..4], tile2 rf[1..5]) ----
    f32x4 bd1[5], bd2[5];
#pragma unroll
    for (int bt = 0; bt < 5; ++bt) { bd1[bt] = fzero4(); bd2[bt] = fzero4(); }
#pragma unroll
    for (int bt = 0; bt < 5; ++bt)
#pragma unroll
      for (int ks = 0; ks < 2; ++ks) {
        bd1[bt] = __builtin_amdgcn_mfma_f32_16x16x32_bf16(rf[bt][ks], qv1[ks], bd1[bt], 0, 0, 0);
        bd2[bt] = __builtin_amdgcn_mfma_f32_16x16x32_bf16(rf[bt + 1][ks], qv2[ks], bd2[bt], 0, 0, 0);
      }

    // ---- V loads issued here: latency hides under chain-1 softmax ----
    bf16x8 vf[4][2];
#pragma unroll
    for (int d = 0; d < 4; ++d)
#pragma unroll
      for (int ks = 0; ks < 2; ++ks)
        vf[d][ks] = *(const bf16x8*)&Vp[(size_t)(d * 16 + l15) * TT + j0 + ks * 32 + lg8];

    // ---- chain 1 ----
#pragma unroll
    for (int bt = 0; bt < 5; ++bt)
#pragma unroll
      for (int rg = 0; rg < 4; ++rg)
        PB[(bt * 16 + lg * 4 + rg) * 18 + l15] = bd1[bt][rg];
    SOFTPV(ac1, i0, o1, m1, l1)

    // ---- chain 2 (re-uses PB/PL after chain-1 reads; per-wave LDS order) ----
#pragma unroll
    for (int bt = 0; bt < 5; ++bt)
#pragma unroll
      for (int rg = 0; rg < 4; ++rg)
        PB[(bt * 16 + lg * 4 + rg) * 18 + l15] = bd2[bt][rg];
    SOFTPV(ac2, i0 + 16, o2, m2, l2)
  }

  // partial epilogue: unnormalized O (bf16) + per-row (m, l)
#pragma unroll
  for (int d = 0; d < 4; ++d)
#pragma unroll
    for (int rg = 0; rg < 4; ++rg) {
      Po[(size_t)(i0 + lg * 4 + rg) * 64 + d * 16 + l15] = (bf16_t)o1[d][rg];
      Po[(size_t)(i0 + 16 + lg * 4 + rg) * 64 + d * 16 + l15] = (bf16_t)o2[d][rg];
    }
  if (lg == 0) { ml[i0 + l15] = make_float2(m1, l1); ml[i0 + 16 + l15] = make_float2(m2, l2); }
}

// ---------------- combine 2 partial chunks -> attnout[t][h*64+dh] ----------------
__global__ __launch_bounds__(256) void combine_kernel(const bf16_t* wsc, bf16_t* wsd) {
  const int gid = blockIdx.x * 256 + threadIdx.x;  // 262144 = 16*2048*8
  const int row = gid >> 3;                        // h*2048 + t
  const int colg = (gid & 7) * 8;
  const float2* mlp = (const float2*)(wsc + OFF_WT);
  const float2 ml0 = mlp[row];
  const float2 ml1 = mlp[16 * TT + row];
  const float M = fmaxf(ml0.x, ml1.x);
  const float e0 = __expf(ml0.x - M), e1 = __expf(ml1.x - M);
  const float inv = 1.f / (ml0.y * e0 + ml1.y * e1);
  bf16x8 o0 = *(const bf16x8*)&wsc[OFF_XB + (size_t)row * 64 + colg];
  bf16x8 o1 = *(const bf16x8*)&wsc[OFF_RB + (size_t)row * 64 + colg];
  const int hh = row >> 11, tt2 = row & 2047;
  bf16x8 r;
#pragma unroll
  for (int i = 0; i < 8; ++i)
    r[i] = (bf16_t)(((float)o0[i] * e0 + (float)o1[i] * e1) * inv);
  *(bf16x8*)&wsd[OFF_AO + (size_t)tt2 * DDIM + hh * 64 + colg] = r;
}

// ---------------- shared 128x128 GEMM core (global_load_lds staging) -------------
__device__ __forceinline__ void gemm128_core(const bf16_t* __restrict__ A,
                                             const bf16_t* __restrict__ Bt,
                                             int i0, int n0, int kbeg, int kend,
                                             f32x4 acc[4][4],
                                             bf16_t* As, bf16_t* Bs) {
  const int tid = threadIdx.x, lane = tid & 63, wv = tid >> 6;
  const int wr = (wv >> 1) * 64, wc = (wv & 1) * 64;
  const int sr = tid >> 2, scc = (tid & 3) * 8;      // LDS dest = tid*16B (linear)
  const int l15 = lane & 15, lg8 = (lane >> 4) * 8;
  for (int k0 = kbeg; k0 < kend; k0 += 32) {
    __syncthreads();
    gload16(&A[(size_t)(i0 + sr) * DDIM + k0 + scc],       &As[sr * 32 + scc]);
    gload16(&A[(size_t)(i0 + 64 + sr) * DDIM + k0 + scc],  &As[(64 + sr) * 32 + scc]);
    gload16(&Bt[(size_t)(n0 + sr) * DDIM + k0 + scc],      &Bs[sr * 32 + scc]);
    gload16(&Bt[(size_t)(n0 + 64 + sr) * DDIM + k0 + scc], &Bs[(64 + sr) * 32 + scc]);
    __syncthreads();
    bf16x8 af[4], bfv[4];
#pragma unroll
    for (int m = 0; m < 4; ++m) af[m] = *(const bf16x8*)&As[(wr + m * 16 + l15) * 32 + lg8];
#pragma unroll
    for (int n = 0; n < 4; ++n) bfv[n] = *(const bf16x8*)&Bs[(wc + n * 16 + l15) * 32 + lg8];
#pragma unroll
    for (int m = 0; m < 4; ++m)
#pragma unroll
      for (int n = 0; n < 4; ++n)
        acc[m][n] = __builtin_amdgcn_mfma_f32_16x16x32_bf16(af[m], bfv[n], acc[m][n], 0, 0, 0);
  }
}

// ---------------- output projection: out += attnout @ Wo (K-split x4, atomic f32) ----------
__global__ __launch_bounds__(256) void outproj_kernel(const bf16_t* wsc, float* __restrict__ outp) {
  const int i0 = blockIdx.x * 128, n0 = blockIdx.y * 128, kz = blockIdx.z;
  const bf16_t* A = wsc + OFF_AO;
  const bf16_t* Bt = wsc + OFF_WT + 4 * SZ_W;
  __shared__ bf16_t As[128 * 32];
  __shared__ bf16_t Bs[128 * 32];
  const int lane = threadIdx.x & 63, wv = threadIdx.x >> 6;
  const int wr = (wv >> 1) * 64, wc = (wv & 1) * 64;
  const int l15 = lane & 15, lr4 = (lane >> 4) * 4;
  f32x4 acc[4][4];
#pragma unroll
  for (int m = 0; m < 4; ++m)
#pragma unroll
    for (int n = 0; n < 4; ++n) acc[m][n] = fzero4();

  gemm128_core(A, Bt, i0, n0, kz * 256, kz * 256 + 256, acc, As, Bs);

#pragma unroll
  for (int mm = 0; mm < 4; ++mm)
#pragma unroll
    for (int nn = 0; nn < 4; ++nn)
#pragma unroll
      for (int rg = 0; rg < 4; ++rg) {
        const int row = i0 + wr + mm * 16 + lr4 + rg;
        const int col = n0 + wc + nn * 16 + l15;
        atomicAdd(&outp[(size_t)row * DDIM + col], acc[mm][nn][rg]);
      }
}

extern "C" void kernel_launch(void* const* d_in, const int* in_sizes, int n_in,
                              void* d_out, int out_size, void* d_ws, size_t ws_size,
                              hipStream_t stream) {
  (void)in_sizes; (void)n_in; (void)out_size; (void)ws_size;
  const float* x    = (const float*)d_in[0];
  const float* remb = (const float*)d_in[1];
  const float* Wq   = (const float*)d_in[2];
  const float* Wk   = (const float*)d_in[3];
  const float* Wv   = (const float*)d_in[4];
  const float* Wr   = (const float*)d_in[5];
  const float* Wo   = (const float*)d_in[6];
  const float* u    = (const float*)d_in[7];
  const float* vb   = (const float*)d_in[8];
  bf16_t* ws = (bf16_t*)d_ws;
  float* outp = (float*)d_out;

  hipMemsetAsync(outp, 0, (size_t)TT * DDIM * sizeof(float), stream);
  convert_kernel<<<dim3(2048), 256, 0, stream>>>(x, remb, ws);
  transpose_w_kernel<<<dim3(16, 16, 5), 256, 0, stream>>>(Wq, Wk, Wv, Wr, Wo, ws);
  proj_kernel<<<dim3(16, 16, 2), 256, 0, stream>>>(ws, ws, u, vb);
  attn_kernel<<<dim3(16, 64, 2), 64, 0, stream>>>(ws, ws);
  combine_kernel<<<dim3(1024), 256, 0, stream>>>(ws, ws);
  outproj_kernel<<<dim3(16, 8, 4), 256, 0, stream>>>(ws, outp);
}

// Round 9
// 224.470 us; speedup vs baseline: 1.2483x; 1.2483x over previous
//
#include <hip/hip_runtime.h>

typedef __bf16 bf16_t;
typedef __bf16 bf16x4v __attribute__((ext_vector_type(4)));
typedef __bf16 bf16x8 __attribute__((ext_vector_type(8)));
typedef float f32x4 __attribute__((ext_vector_type(4)));

constexpr int TT = 2048;
constexpr int DDIM = 1024;

// workspace layout (bf16 element offsets)
constexpr size_t SZ_TD  = (size_t)2048 * 1024;
constexpr size_t OFF_QU = 0;                     // Qu[h][t][dh] = q + u
constexpr size_t OFF_QV = 1 * SZ_TD;             // Qv[h][t][dh] = q + v_bias
constexpr size_t OFF_KK = 2 * SZ_TD;             // K [h][t][dh]
constexpr size_t OFF_RR = 3 * SZ_TD;             // Rrev[h][c][dh] = R[T-1-c]
constexpr size_t OFF_VT = 4 * SZ_TD;             // Vt[h][dh][t]
constexpr size_t OFF_AO = 5 * SZ_TD;             // attnout[t][d]
constexpr size_t OFF_XB = 6 * SZ_TD;             // x bf16; REUSED: attn partial O chunk 0
constexpr size_t OFF_RB = 7 * SZ_TD;             // r_emb ; REUSED: attn partial O chunk 1
constexpr size_t OFF_WT = 8 * SZ_TD;             // Wt[5][n][k]; after proj: Wq slot = ml float2
constexpr size_t SZ_W   = (size_t)1024 * 1024;

__device__ __forceinline__ f32x4 fzero4() {
  f32x4 z; z[0] = 0.f; z[1] = 0.f; z[2] = 0.f; z[3] = 0.f; return z;
}

__device__ __forceinline__ void gload16(const bf16_t* g, bf16_t* l) {
  __builtin_amdgcn_global_load_lds((const __attribute__((address_space(1))) void*)g,
                                   (__attribute__((address_space(3))) void*)l, 16, 0, 0);
}

// ---------------- prep 1: fp32 -> bf16 for x and r_emb ----------------
__global__ __launch_bounds__(256) void convert_kernel(const float* __restrict__ x,
                                                      const float* __restrict__ r,
                                                      bf16_t* __restrict__ ws) {
  const int i = blockIdx.x * 256 + threadIdx.x;
  float4 a = ((const float4*)x)[i];
  float4 b = ((const float4*)r)[i];
  bf16x4v av, bv;
  av[0] = (bf16_t)a.x; av[1] = (bf16_t)a.y; av[2] = (bf16_t)a.z; av[3] = (bf16_t)a.w;
  bv[0] = (bf16_t)b.x; bv[1] = (bf16_t)b.y; bv[2] = (bf16_t)b.z; bv[3] = (bf16_t)b.w;
  ((bf16x4v*)(ws + OFF_XB))[i] = av;
  ((bf16x4v*)(ws + OFF_RB))[i] = bv;
}

// ---------------- prep 2: W[k][n] fp32 -> Wt[n][k] bf16, 5 weights ----------------
__global__ __launch_bounds__(256) void transpose_w_kernel(const float* __restrict__ Wq,
                                                          const float* __restrict__ Wk,
                                                          const float* __restrict__ Wv,
                                                          const float* __restrict__ Wr,
                                                          const float* __restrict__ Wo,
                                                          bf16_t* __restrict__ ws) {
  const int k0 = blockIdx.x * 64, n0 = blockIdx.y * 64, wsel = blockIdx.z;
  const float* W = (wsel == 0) ? Wq : (wsel == 1) ? Wk : (wsel == 2) ? Wv : (wsel == 3) ? Wr : Wo;
  bf16_t* Wt = ws + OFF_WT + (size_t)wsel * SZ_W;
  __shared__ float tile[64][65];
  const int tid = threadIdx.x;
#pragma unroll
  for (int it = 0; it < 4; ++it) {
    int g = tid + it * 256; int rr = g >> 4; int c4 = (g & 15) * 4;
    float4 v = *(const float4*)&W[(size_t)(k0 + rr) * DDIM + n0 + c4];
    tile[rr][c4] = v.x; tile[rr][c4 + 1] = v.y; tile[rr][c4 + 2] = v.z; tile[rr][c4 + 3] = v.w;
  }
  __syncthreads();
#pragma unroll
  for (int it = 0; it < 4; ++it) {
    int g = tid + it * 256; int nr = g >> 4; int c4 = (g & 15) * 4;
    bf16x4v o;
    o[0] = (bf16_t)tile[c4 + 0][nr]; o[1] = (bf16_t)tile[c4 + 1][nr];
    o[2] = (bf16_t)tile[c4 + 2][nr]; o[3] = (bf16_t)tile[c4 + 3][nr];
    *(bf16x4v*)&Wt[(size_t)(n0 + nr) * DDIM + k0 + c4] = o;
  }
}

// ---------------- projections (128x64 tile): z=0 Q(->Qu,Qv), 1 K, 2 V(->Vt), 3 R(->Rrev) ---
__global__ __launch_bounds__(256) void proj_kernel(const bf16_t* wsc, bf16_t* wsd,
                                                   const float* __restrict__ u,
                                                   const float* __restrict__ vb) {
  const int z = blockIdx.z;
  const int i0 = blockIdx.x * 128, n0 = blockIdx.y * 64;
  const bf16_t* A = wsc + ((z == 3) ? OFF_RB : OFF_XB);
  const bf16_t* Bt = wsc + OFF_WT + (size_t)z * SZ_W;
  __shared__ bf16_t As[128 * 32];
  __shared__ bf16_t Bs[64 * 32];
  const int tid = threadIdx.x, lane = tid & 63, wv = tid >> 6;
  const int wr = (wv >> 1) * 64, wc = (wv & 1) * 32;
  const int sr = tid >> 2, scc = (tid & 3) * 8;
  const int l15 = lane & 15, lg8 = (lane >> 4) * 8, lr4 = (lane >> 4) * 4;
  f32x4 acc[4][2];
#pragma unroll
  for (int m = 0; m < 4; ++m)
#pragma unroll
    for (int n = 0; n < 2; ++n) acc[m][n] = fzero4();

  for (int k0 = 0; k0 < DDIM; k0 += 32) {
    __syncthreads();
    gload16(&A[(size_t)(i0 + sr) * DDIM + k0 + scc],      &As[sr * 32 + scc]);
    gload16(&A[(size_t)(i0 + 64 + sr) * DDIM + k0 + scc], &As[(64 + sr) * 32 + scc]);
    gload16(&Bt[(size_t)(n0 + sr) * DDIM + k0 + scc],     &Bs[sr * 32 + scc]);
    __syncthreads();
    bf16x8 af[4], bfv[2];
#pragma unroll
    for (int m = 0; m < 4; ++m) af[m] = *(const bf16x8*)&As[(wr + m * 16 + l15) * 32 + lg8];
#pragma unroll
    for (int n = 0; n < 2; ++n) bfv[n] = *(const bf16x8*)&Bs[(wc + n * 16 + l15) * 32 + lg8];
#pragma unroll
    for (int m = 0; m < 4; ++m)
#pragma unroll
      for (int n = 0; n < 2; ++n)
        acc[m][n] = __builtin_amdgcn_mfma_f32_16x16x32_bf16(af[m], bfv[n], acc[m][n], 0, 0, 0);
  }

#pragma unroll
  for (int mm = 0; mm < 4; ++mm)
#pragma unroll
    for (int nn = 0; nn < 2; ++nn)
#pragma unroll
      for (int rg = 0; rg < 4; ++rg) {
        const int row = i0 + wr + mm * 16 + lr4 + rg;
        const int col = n0 + wc + nn * 16 + l15;
        const float val = acc[mm][nn][rg];
        const int hh = col >> 6, dh = col & 63;
        if (z == 0) {
          wsd[OFF_QU + ((size_t)hh * TT + row) * 64 + dh] = (bf16_t)(val + u[col]);
          wsd[OFF_QV + ((size_t)hh * TT + row) * 64 + dh] = (bf16_t)(val + vb[col]);
        } else if (z == 1) {
          wsd[OFF_KK + ((size_t)hh * TT + row) * 64 + dh] = (bf16_t)val;
        } else if (z == 2) {
          wsd[OFF_VT + ((size_t)hh * 64 + dh) * TT + row] = (bf16_t)val;
        } else {
          wsd[OFF_RR + ((size_t)hh * TT + (TT - 1 - row)) * 64 + dh] = (bf16_t)val;
        }
      }
}

// ---------------- fused XL attention: 2 interleaved q16-tiles per wave, K dbuf -------------
#define LOADK(DST, JJ)                                                                     \
  _Pragma("unroll") for (int nt_ = 0; nt_ < 4; ++nt_)                                      \
  _Pragma("unroll") for (int ks_ = 0; ks_ < 2; ++ks_)                                      \
    DST[nt_][ks_] = *(const bf16x8*)&Kp[(size_t)((JJ) + nt_ * 16 + l15) * 64 + ks_ * 32 + lg8];

#define SOFTPV(AC, PBX, PLX, QBASE, OO, MRUN, LRUN)                                        \
  {                                                                                        \
    float sc[4][4];                                                                        \
    float smax = -3e38f;                                                                   \
    _Pragma("unroll") for (int nt = 0; nt < 4; ++nt)                                       \
      _Pragma("unroll") for (int rg = 0; rg < 4; ++rg) {                                   \
        const int jj = nt * 16 + lg * 4 + rg;                                              \
        float v = (AC[nt][rg] + PBX[(l15 + 63 - jj) * 18 + l15]) * 0.125f;                 \
        v = (j0 + jj > (QBASE) + l15) ? -1e30f : v;                                        \
        smax = fmaxf(smax, v);                                                             \
        sc[nt][rg] = v;                                                                    \
      }                                                                                    \
    smax = fmaxf(smax, __shfl_xor(smax, 16));                                              \
    smax = fmaxf(smax, __shfl_xor(smax, 32));                                              \
    const float newm = fmaxf(MRUN, smax);                                                  \
    const float fac = __expf(MRUN - newm);                                                 \
    MRUN = newm;                                                                           \
    float pv[4][4];                                                                        \
    float rsum = 0.f;                                                                      \
    _Pragma("unroll") for (int nt = 0; nt < 4; ++nt)                                       \
      _Pragma("unroll") for (int rg = 0; rg < 4; ++rg) {                                   \
        pv[nt][rg] = __expf(sc[nt][rg] - newm);                                            \
        rsum += pv[nt][rg];                                                                \
      }                                                                                    \
    rsum += __shfl_xor(rsum, 16);                                                          \
    rsum += __shfl_xor(rsum, 32);                                                          \
    LRUN = LRUN * fac + rsum;                                                              \
    float fo[4];                                                                           \
    _Pragma("unroll") for (int rg = 0; rg < 4; ++rg) fo[rg] = __shfl(fac, lg * 4 + rg);    \
    _Pragma("unroll") for (int d = 0; d < 4; ++d)                                          \
      _Pragma("unroll") for (int rg = 0; rg < 4; ++rg) OO[d][rg] *= fo[rg];                \
    _Pragma("unroll") for (int nt = 0; nt < 4; ++nt) {                                     \
      bf16x4v pk;                                                                          \
      pk[0] = (bf16_t)pv[nt][0]; pk[1] = (bf16_t)pv[nt][1];                                \
      pk[2] = (bf16_t)pv[nt][2]; pk[3] = (bf16_t)pv[nt][3];                                \
      *(bf16x4v*)&PLX[l15 * 72 + nt * 16 + lg * 4] = pk;                                   \
    }                                                                                      \
    bf16x8 pf[2];                                                                          \
    _Pragma("unroll") for (int ks = 0; ks < 2; ++ks)                                       \
      pf[ks] = *(const bf16x8*)&PLX[l15 * 72 + ks * 32 + lg8];                             \
    _Pragma("unroll") for (int d = 0; d < 4; ++d)                                          \
      _Pragma("unroll") for (int ks = 0; ks < 2; ++ks)                                     \
        OO[d] = __builtin_amdgcn_mfma_f32_16x16x32_bf16(pf[ks], vf[d][ks], OO[d], 0, 0, 0);\
  }

#define ATTN_BODY(KC, KN, J0, JN)                                                          \
  {                                                                                        \
    const int j0 = (J0);                                                                   \
    bf16x8 rf[6][2], vf[4][2];                                                             \
    const int c0 = i0 - j0 - 63;                                                           \
    _Pragma("unroll") for (int bt = 0; bt < 6; ++bt) {                                     \
      int c = c0 + bt * 16 + l15;                                                          \
      c = (c < 0) ? 0 : ((c > TT - 1) ? TT - 1 : c);                                       \
      _Pragma("unroll") for (int ks = 0; ks < 2; ++ks)                                     \
        rf[bt][ks] = *(const bf16x8*)&Rp[(size_t)c * 64 + ks * 32 + lg8];                  \
    }                                                                                      \
    _Pragma("unroll") for (int d = 0; d < 4; ++d)                                          \
      _Pragma("unroll") for (int ks = 0; ks < 2; ++ks)                                     \
        vf[d][ks] = *(const bf16x8*)&Vp[(size_t)(d * 16 + l15) * TT + j0 + ks * 32 + lg8]; \
    LOADK(KN, JN)                                                                          \
    f32x4 ac1[4], ac2[4];                                                                  \
    _Pragma("unroll") for (int nt = 0; nt < 4; ++nt) { ac1[nt] = fzero4(); ac2[nt] = fzero4(); } \
    _Pragma("unroll") for (int nt = 0; nt < 4; ++nt)                                       \
      _Pragma("unroll") for (int ks = 0; ks < 2; ++ks) {                                   \
        ac1[nt] = __builtin_amdgcn_mfma_f32_16x16x32_bf16(KC[nt][ks], qu1[ks], ac1[nt], 0, 0, 0); \
        ac2[nt] = __builtin_amdgcn_mfma_f32_16x16x32_bf16(KC[nt][ks], qu2[ks], ac2[nt], 0, 0, 0); \
      }                                                                                    \
    f32x4 bd1[5], bd2[5];                                                                  \
    _Pragma("unroll") for (int bt = 0; bt < 5; ++bt) { bd1[bt] = fzero4(); bd2[bt] = fzero4(); } \
    _Pragma("unroll") for (int bt = 0; bt < 5; ++bt)                                       \
      _Pragma("unroll") for (int ks = 0; ks < 2; ++ks) {                                   \
        bd1[bt] = __builtin_amdgcn_mfma_f32_16x16x32_bf16(rf[bt][ks], qv1[ks], bd1[bt], 0, 0, 0); \
        bd2[bt] = __builtin_amdgcn_mfma_f32_16x16x32_bf16(rf[bt + 1][ks], qv2[ks], bd2[bt], 0, 0, 0); \
      }                                                                                    \
    _Pragma("unroll") for (int bt = 0; bt < 5; ++bt)                                       \
      _Pragma("unroll") for (int rg = 0; rg < 4; ++rg) {                                   \
        PB1[(bt * 16 + lg * 4 + rg) * 18 + l15] = bd1[bt][rg];                             \
        PB2[(bt * 16 + lg * 4 + rg) * 18 + l15] = bd2[bt][rg];                             \
      }                                                                                    \
    SOFTPV(ac1, PB1, PL1, i0, o1, m1, l1)                                                  \
    SOFTPV(ac2, PB2, PL2, i0 + 16, o2, m2, l2)                                             \
  }

// grid (16, 64, 2): blockIdx.x = head -> linear id % 8 == h % 8 -> head-per-XCD affinity.
__global__ __launch_bounds__(64) void attn_kernel(const bf16_t* wsc, bf16_t* wsd) {
  const int h = blockIdx.x;
  const int chunk = blockIdx.z;
  const int q32 = 63 - blockIdx.y;         // longest blocks first
  const int i0 = q32 * 32;                 // tile1 rows i0..i0+15, tile2 rows i0+16..i0+31
  const int lane = threadIdx.x & 63;
  const int l15 = lane & 15;
  const int lg = lane >> 4;
  const int lg8 = lg * 8;

  const int NT = (i0 >> 6) + 1;
  const int H = (NT + 1) >> 1;
  const int tbeg = chunk ? H : 0;
  const int tend = chunk ? NT : H;

  bf16_t* Po = wsd + ((chunk == 0) ? OFF_XB : OFF_RB) + (size_t)h * TT * 64;
  float2* ml = (float2*)(wsd + OFF_WT) + (size_t)(chunk * 16 + h) * TT;

  if (tbeg >= tend) {                      // empty chunk: neutral partial (32 rows)
#pragma unroll
    for (int m = 0; m < 2; ++m)
#pragma unroll
      for (int d = 0; d < 4; ++d)
#pragma unroll
        for (int rg = 0; rg < 4; ++rg)
          Po[(size_t)(i0 + m * 16 + lg * 4 + rg) * 64 + d * 16 + l15] = (bf16_t)0.f;
    if (lg == 0) { ml[i0 + l15] = make_float2(-3e38f, 0.f); ml[i0 + 16 + l15] = make_float2(-3e38f, 0.f); }
    return;
  }

  const bf16_t* QUp = wsc + OFF_QU + (size_t)h * TT * 64;
  const bf16_t* QVp = wsc + OFF_QV + (size_t)h * TT * 64;
  const bf16_t* Kp  = wsc + OFF_KK + (size_t)h * TT * 64;
  const bf16_t* Rp  = wsc + OFF_RR + (size_t)h * TT * 64;
  const bf16_t* Vp  = wsc + OFF_VT + (size_t)h * 64 * TT;

  __shared__ float PB1[80 * 18];           // stride 18 -> only free 2-way conflicts
  __shared__ float PB2[80 * 18];
  __shared__ bf16_t PL1[16 * 72];
  __shared__ bf16_t PL2[16 * 72];

  bf16x8 qu1[2], qv1[2], qu2[2], qv2[2];
#pragma unroll
  for (int ks = 0; ks < 2; ++ks) {
    qu1[ks] = *(const bf16x8*)&QUp[(size_t)(i0 + l15) * 64 + ks * 32 + lg8];
    qv1[ks] = *(const bf16x8*)&QVp[(size_t)(i0 + l15) * 64 + ks * 32 + lg8];
    qu2[ks] = *(const bf16x8*)&QUp[(size_t)(i0 + 16 + l15) * 64 + ks * 32 + lg8];
    qv2[ks] = *(const bf16x8*)&QVp[(size_t)(i0 + 16 + l15) * 64 + ks * 32 + lg8];
  }

  f32x4 o1[4], o2[4];
#pragma unroll
  for (int d = 0; d < 4; ++d) { o1[d] = fzero4(); o2[d] = fzero4(); }
  float m1 = -3e38f, l1 = 0.f, m2 = -3e38f, l2 = 0.f;

  bf16x8 kA[4][2], kB[4][2];
  LOADK(kA, tbeg * 64)

  int t = tbeg;
  while (true) {
    int tn = (t + 1 < tend) ? t + 1 : t;
    ATTN_BODY(kA, kB, t * 64, tn * 64)
    if (++t >= tend) break;
    tn = (t + 1 < tend) ? t + 1 : t;
    ATTN_BODY(kB, kA, t * 64, tn * 64)
    if (++t >= tend) break;
  }

  // partial epilogue: unnormalized O (bf16) + per-row (m, l)
#pragma unroll
  for (int d = 0; d < 4; ++d)
#pragma unroll
    for (int rg = 0; rg < 4; ++rg) {
      Po[(size_t)(i0 + lg * 4 + rg) * 64 + d * 16 + l15] = (bf16_t)o1[d][rg];
      Po[(size_t)(i0 + 16 + lg * 4 + rg) * 64 + d * 16 + l15] = (bf16_t)o2[d][rg];
    }
  if (lg == 0) { ml[i0 + l15] = make_float2(m1, l1); ml[i0 + 16 + l15] = make_float2(m2, l2); }
}

// ---------------- combine 2 partial chunks -> attnout[t][h*64+dh] ----------------
__global__ __launch_bounds__(256) void combine_kernel(const bf16_t* wsc, bf16_t* wsd) {
  const int gid = blockIdx.x * 256 + threadIdx.x;  // 262144 = 16*2048*8
  const int row = gid >> 3;                        // h*2048 + t
  const int colg = (gid & 7) * 8;
  const float2* mlp = (const float2*)(wsc + OFF_WT);
  const float2 ml0 = mlp[row];
  const float2 ml1 = mlp[16 * TT + row];
  const float M = fmaxf(ml0.x, ml1.x);
  const float e0 = __expf(ml0.x - M), e1 = __expf(ml1.x - M);
  const float inv = 1.f / (ml0.y * e0 + ml1.y * e1);
  bf16x8 o0 = *(const bf16x8*)&wsc[OFF_XB + (size_t)row * 64 + colg];
  bf16x8 o1 = *(const bf16x8*)&wsc[OFF_RB + (size_t)row * 64 + colg];
  const int hh = row >> 11, tt2 = row & 2047;
  bf16x8 r;
#pragma unroll
  for (int i = 0; i < 8; ++i)
    r[i] = (bf16_t)(((float)o0[i] * e0 + (float)o1[i] * e1) * inv);
  *(bf16x8*)&wsd[OFF_AO + (size_t)tt2 * DDIM + hh * 64 + colg] = r;
}

// ---------------- shared 128x128 GEMM core (global_load_lds staging) -------------
__device__ __forceinline__ void gemm128_core(const bf16_t* __restrict__ A,
                                             const bf16_t* __restrict__ Bt,
                                             int i0, int n0, int kbeg, int kend,
                                             f32x4 acc[4][4],
                                             bf16_t* As, bf16_t* Bs) {
  const int tid = threadIdx.x, lane = tid & 63, wv = tid >> 6;
  const int wr = (wv >> 1) * 64, wc = (wv & 1) * 64;
  const int sr = tid >> 2, scc = (tid & 3) * 8;      // LDS dest = tid*16B (linear)
  const int l15 = lane & 15, lg8 = (lane >> 4) * 8;
  for (int k0 = kbeg; k0 < kend; k0 += 32) {
    __syncthreads();
    gload16(&A[(size_t)(i0 + sr) * DDIM + k0 + scc],       &As[sr * 32 + scc]);
    gload16(&A[(size_t)(i0 + 64 + sr) * DDIM + k0 + scc],  &As[(64 + sr) * 32 + scc]);
    gload16(&Bt[(size_t)(n0 + sr) * DDIM + k0 + scc],      &Bs[sr * 32 + scc]);
    gload16(&Bt[(size_t)(n0 + 64 + sr) * DDIM + k0 + scc], &Bs[(64 + sr) * 32 + scc]);
    __syncthreads();
    bf16x8 af[4], bfv[4];
#pragma unroll
    for (int m = 0; m < 4; ++m) af[m] = *(const bf16x8*)&As[(wr + m * 16 + l15) * 32 + lg8];
#pragma unroll
    for (int n = 0; n < 4; ++n) bfv[n] = *(const bf16x8*)&Bs[(wc + n * 16 + l15) * 32 + lg8];
#pragma unroll
    for (int m = 0; m < 4; ++m)
#pragma unroll
      for (int n = 0; n < 4; ++n)
        acc[m][n] = __builtin_amdgcn_mfma_f32_16x16x32_bf16(af[m], bfv[n], acc[m][n], 0, 0, 0);
  }
}

// ---------------- output projection: out += attnout @ Wo (K-split x4, atomic f32) ----------
__global__ __launch_bounds__(256) void outproj_kernel(const bf16_t* wsc, float* __restrict__ outp) {
  const int i0 = blockIdx.x * 128, n0 = blockIdx.y * 128, kz = blockIdx.z;
  const bf16_t* A = wsc + OFF_AO;
  const bf16_t* Bt = wsc + OFF_WT + 4 * SZ_W;
  __shared__ bf16_t As[128 * 32];
  __shared__ bf16_t Bs[128 * 32];
  const int lane = threadIdx.x & 63, wv = threadIdx.x >> 6;
  const int wr = (wv >> 1) * 64, wc = (wv & 1) * 64;
  const int l15 = lane & 15, lr4 = (lane >> 4) * 4;
  f32x4 acc[4][4];
#pragma unroll
  for (int m = 0; m < 4; ++m)
#pragma unroll
    for (int n = 0; n < 4; ++n) acc[m][n] = fzero4();

  gemm128_core(A, Bt, i0, n0, kz * 256, kz * 256 + 256, acc, As, Bs);

#pragma unroll
  for (int mm = 0; mm < 4; ++mm)
#pragma unroll
    for (int nn = 0; nn < 4; ++nn)
#pragma unroll
      for (int rg = 0; rg < 4; ++rg) {
        const int row = i0 + wr + mm * 16 + lr4 + rg;
        const int col = n0 + wc + nn * 16 + l15;
        atomicAdd(&outp[(size_t)row * DDIM + col], acc[mm][nn][rg]);
      }
}

extern "C" void kernel_launch(void* const* d_in, const int* in_sizes, int n_in,
                              void* d_out, int out_size, void* d_ws, size_t ws_size,
                              hipStream_t stream) {
  (void)in_sizes; (void)n_in; (void)out_size; (void)ws_size;
  const float* x    = (const float*)d_in[0];
  const float* remb = (const float*)d_in[1];
  const float* Wq   = (const float*)d_in[2];
  const float* Wk   = (const float*)d_in[3];
  const float* Wv   = (const float*)d_in[4];
  const float* Wr   = (const float*)d_in[5];
  const float* Wo   = (const float*)d_in[6];
  const float* u    = (const float*)d_in[7];
  const float* vb   = (const float*)d_in[8];
  bf16_t* ws = (bf16_t*)d_ws;
  float* outp = (float*)d_out;

  hipMemsetAsync(outp, 0, (size_t)TT * DDIM * sizeof(float), stream);
  convert_kernel<<<dim3(2048), 256, 0, stream>>>(x, remb, ws);
  transpose_w_kernel<<<dim3(16, 16, 5), 256, 0, stream>>>(Wq, Wk, Wv, Wr, Wo, ws);
  proj_kernel<<<dim3(16, 16, 4), 256, 0, stream>>>(ws, ws, u, vb);
  attn_kernel<<<dim3(16, 64, 2), 64, 0, stream>>>(ws, ws);
  combine_kernel<<<dim3(1024), 256, 0, stream>>>(ws, ws);
  outproj_kernel<<<dim3(16, 8, 4), 256, 0, stream>>>(ws, outp);
}